// Round 10
// baseline (89.881 us; speedup 1.0000x reference)
//
#include <hip/hip_runtime.h>
#include <hip/hip_bf16.h>

typedef __attribute__((ext_vector_type(4))) float f32x4;
typedef __attribute__((ext_vector_type(8))) short bf16x8;
typedef __attribute__((ext_vector_type(4))) short s16x4;

#define NB 4              // items per block in kernel A
#define CORR_OFF_F 4096   // corr starts at byte 16384 in ws (float index)

template<bool ISF32>
__device__ __forceinline__ float ldin(const void* p, int i) {
    if constexpr (ISF32) return ((const float*)p)[i];
    else return __bfloat162float(((const __hip_bfloat16*)p)[i]);
}

template<bool ISF32>
__device__ __forceinline__ f32x4 ldq(const void* p, int i) {
    if constexpr (ISF32) return *(const f32x4*)((const float*)p + i);
    else {
        const __hip_bfloat16* q = (const __hip_bfloat16*)p + i;
        return (f32x4){__bfloat162float(q[0]), __bfloat162float(q[1]),
                       __bfloat162float(q[2]), __bfloat162float(q[3])};
    }
}

__device__ __forceinline__ short bf16bits(float v) {
    __hip_bfloat16 h = __float2bfloat16(v);
    return *(const short*)&h;
}
__device__ __forceinline__ float bf16val(short s) {
    return __bfloat162float(*(const __hip_bfloat16*)&s);
}

__device__ __forceinline__ bool word_looks_bf16(unsigned int w) {
    const unsigned int lo = w & 0xFFFFu;
    const unsigned int ex = (lo >> 7) & 0xFFu;
    return (ex >= 100u && ex <= 140u) || (lo & 0x7FFFu) == 0u;
}

__device__ __forceinline__ bool vote_isf32(const void* hidden, int t) {
    const unsigned int* hw = (const unsigned int*)hidden;
    const bool pass = word_looks_bf16(hw[t & 31]);
    const unsigned long long m = __ballot(pass);
    return __popcll(m) < 32;
}

// ---- W2 swizzle into MFMA B-fragment order, split hi/lo bf16 ----
// wsfrag[((ks*4+nt)*64+lane)*8 + j] (hi), +4096 (lo)
template<bool ISF32>
__device__ void w2prep_body(const void* w2, short* wsfrag, int idx0) {
    #pragma unroll
    for (int i = 0; i < 2; ++i) {
        const int idx = idx0 + i * 2048;            // 0..4095
        const int j = idx & 7;
        const int lane = (idx >> 3) & 63;
        const int nt = (idx >> 9) & 3;
        const int ks = idx >> 11;
        const int src = (ks * 32 + (lane >> 4) * 8 + j) * 64 + nt * 16 + (lane & 15);
        const float v = ldin<ISF32>(w2, src);
        const short hb = bf16bits(v);
        wsfrag[idx] = hb;
        wsfrag[4096 + idx] = bf16bits(v - bf16val(hb));
    }
}

// ======================= Kernel A: corr producer =======================
struct SmemA {
    float inp[NB][384];
    float part[4][NB][64];
    float baseAll[NB][64];
    float sub[NB][8][64];
    int   sel[NB][8];
};

template<bool ISF32>
__device__ void qtranA_body(SmemA& sm,
    const void* __restrict__ hidden, const void* __restrict__ actions,
    const void* __restrict__ w1, const void* __restrict__ b1,
    const void* __restrict__ w2, float* __restrict__ ws, int blk, int t)
{
    const int lane = t & 63;
    const int wv = t >> 6;
    const int fq = lane & 15;
    const int rofs = lane >> 4;
    const int b0 = blk * NB;

    // ---- stage 4 input vectors ----
    {
        const int i0 = t >> 6, s = t & 63;
        const int j = s >> 3, k4 = (s & 7) * 4;
        *(f32x4*)&sm.inp[i0][j * 48 + k4] =
            ldq<ISF32>(hidden, ((b0 + i0) * 8 + j) * 32 + k4);
        if (s < 32) {
            const int ja = s >> 2, c4 = (s & 3) * 4;
            *(f32x4*)&sm.inp[i0][ja * 48 + 32 + c4] =
                ldq<ISF32>(actions, ((b0 + i0) * 8 + ja) * 16 + c4);
        }
    }
    __syncthreads();

    // ---- sel detect (one-hot) ----
    {
        const int i0 = t >> 6, s = t & 63, a = s & 15;
        const int g1 = s >> 4;
        if (sm.inp[i0][g1 * 48 + 32 + a] > 0.5f) sm.sel[i0][g1] = a;
        const int g2 = g1 + 4;
        if (sm.inp[i0][g2 * 48 + 32 + a] > 0.5f) sm.sel[i0][g2] = a;
    }

    // ---- layer-1 hidden partials: wave wv covers 64 of 256 hidden rows ----
    {
        f32x4 a4[NB];
        #pragma unroll
        for (int i = 0; i < NB; ++i) a4[i] = (f32x4){0.f, 0.f, 0.f, 0.f};
        #pragma unroll 8
        for (int p = 0; p < 16; ++p) {
            const int hr = wv * 64 + p * 4 + rofs;
            const int r = (hr >> 5) * 48 + (hr & 31);
            const f32x4 wq = ldq<ISF32>(w1, r * 64 + fq * 4);
            #pragma unroll
            for (int i = 0; i < NB; ++i) {
                const float xv = sm.inp[i][r];
                #pragma unroll
                for (int c = 0; c < 4; ++c) a4[i][c] = fmaf(xv, wq[c], a4[i][c]);
            }
        }
        #pragma unroll
        for (int i = 0; i < NB; ++i)
          #pragma unroll
          for (int c = 0; c < 4; ++c) {
            a4[i][c] += __shfl_xor(a4[i][c], 16);
            a4[i][c] += __shfl_xor(a4[i][c], 32);
          }
        if (rofs == 0) {
            #pragma unroll
            for (int i = 0; i < NB; ++i)
                *(f32x4*)&sm.part[wv][i][fq * 4] = a4[i];
        }
    }
    __syncthreads();

    // ---- sub rows (gather from w1, L2-hot) ----
    #pragma unroll
    for (int p = 0; p < 2; ++p) {
        const int idx = p * 256 + t;                 // 0..511
        const int i = idx >> 7, g = (idx >> 4) & 7, qd = idx & 15;
        *(f32x4*)&sm.sub[i][g][qd * 4] =
            ldq<ISF32>(w1, (g * 48 + 32 + sm.sel[i][g]) * 64 + qd * 4);
    }
    __syncthreads();

    // ---- baseAll = b1 + hidden partials + sum_g sub ----
    {
        const int i = t >> 6, f = t & 63;
        float v = ldin<ISF32>(b1, f);
        #pragma unroll
        for (int w = 0; w < 4; ++w) v += sm.part[w][i][f];
        #pragma unroll
        for (int g = 0; g < 8; ++g) v += sm.sub[i][g][f];
        sm.baseAll[i][f] = v;
    }
    __syncthreads();

    // ---- corr[b][g][f] = baseAll - sub -> ws ----
    #pragma unroll
    for (int p = 0; p < 2; ++p) {
        const int idx = p * 256 + t;                 // 0..511 (f32x4 units)
        const int i = idx >> 7, g = (idx >> 4) & 7, qd = idx & 15;
        const f32x4 ba = *(const f32x4*)&sm.baseAll[i][qd * 4];
        const f32x4 sb = *(const f32x4*)&sm.sub[i][g][qd * 4];
        const f32x4 c = (f32x4){ba[0] - sb[0], ba[1] - sb[1],
                                ba[2] - sb[2], ba[3] - sb[3]};
        *(f32x4*)&ws[CORR_OFF_F + ((b0 + i) * 8 + g) * 64 + qd * 4] = c;
    }

    // ---- blocks 0..7: W2 fragment prep (independent of the above) ----
    if (blk < 8)
        w2prep_body<ISF32>(w2, (short*)ws, blk * 256 + t);
}

__global__ __launch_bounds__(256, 2) void qtranA_kernel(
    const void* __restrict__ hidden, const void* __restrict__ actions,
    const void* __restrict__ w1, const void* __restrict__ b1,
    const void* __restrict__ w2, float* __restrict__ ws)
{
    __shared__ SmemA sm;
    const int t = threadIdx.x;
    if (vote_isf32(hidden, t))
        qtranA_body<true>(sm, hidden, actions, w1, b1, w2, ws, blockIdx.x, t);
    else
        qtranA_body<false>(sm, hidden, actions, w1, b1, w2, ws, blockIdx.x, t);
}

// ======================= Kernel B: MFMA consumer =======================
template<bool ISF32>
__device__ void qtranB_body(float (&corr_s)[8][64],
    const void* __restrict__ w1, const void* __restrict__ b2,
    const void* __restrict__ w3, const void* __restrict__ b3,
    void* __restrict__ out, const float* __restrict__ ws, int b, int t)
{
    const int lane = t & 63;
    const int wv = t >> 6;
    const int q = lane >> 4;
    const int n = lane & 15;

    // ---- issue ALL global loads up front (none depends on LDS) ----
    // W1 action rows for this thread's 2 items (g=2wv+mt, a=n)
    f32x4 wr[2][2][2];   // [mt][ks][half]
    #pragma unroll
    for (int mt = 0; mt < 2; ++mt) {
        const int row = ((wv * 2 + mt) * 48 + 32 + n) * 64;
        #pragma unroll
        for (int ks = 0; ks < 2; ++ks) {
            wr[mt][ks][0] = ldq<ISF32>(w1, row + ks * 32 + q * 8);
            wr[mt][ks][1] = ldq<ISF32>(w1, row + ks * 32 + q * 8 + 4);
        }
    }
    float b2f[4], w3f[4];
    #pragma unroll
    for (int nt = 0; nt < 4; ++nt) {
        b2f[nt] = ldin<ISF32>(b2, nt * 16 + n);
        w3f[nt] = ldin<ISF32>(w3, nt * 16 + n);
    }
    const float b3f = ldin<ISF32>(b3, 0);

    // corr -> LDS (2 KB)
    if (t < 128) {
        const int g = t >> 4, qd = t & 15;
        *(f32x4*)&corr_s[g][qd * 4] =
            *(const f32x4*)&ws[CORR_OFF_F + (b * 8 + g) * 64 + qd * 4];
    }
    __syncthreads();

    // ---- A-fragments in registers: h1 = relu(corr[g] + W1row) ----
    bf16x8 af[2][2];     // [ks][mt]
    #pragma unroll
    for (int mt = 0; mt < 2; ++mt) {
        const int g = wv * 2 + mt;
        #pragma unroll
        for (int ks = 0; ks < 2; ++ks)
          #pragma unroll
          for (int h = 0; h < 2; ++h) {
            const int f0 = ks * 32 + q * 8 + h * 4;
            const f32x4 cc = *(const f32x4*)&corr_s[g][f0];
            const f32x4 w4 = wr[mt][ks][h];
            #pragma unroll
            for (int c = 0; c < 4; ++c)
                af[ks][mt][h * 4 + c] = bf16bits(fmaxf(cc[c] + w4[c], 0.f));
          }
    }

    // ---- layer 2: split-W2 mfma_f32_16x16x32_bf16 ----
    f32x4 acc[2][4];
    #pragma unroll
    for (int mt = 0; mt < 2; ++mt)
      #pragma unroll
      for (int nt = 0; nt < 4; ++nt)
        acc[mt][nt] = (f32x4){0.f, 0.f, 0.f, 0.f};

    const short* wsfrag = (const short*)ws;
    #pragma unroll
    for (int ks = 0; ks < 2; ++ks) {
        bf16x8 bhi[4], blo[4];
        #pragma unroll
        for (int nt = 0; nt < 4; ++nt) {
            const int fb = ((ks * 4 + nt) * 64 + lane) * 8;
            bhi[nt] = *(const bf16x8*)&wsfrag[fb];
            blo[nt] = *(const bf16x8*)&wsfrag[4096 + fb];
        }
        #pragma unroll
        for (int nt = 0; nt < 4; ++nt)
          #pragma unroll
          for (int mt = 0; mt < 2; ++mt) {
            acc[mt][nt] = __builtin_amdgcn_mfma_f32_16x16x32_bf16(
                af[ks][mt], bhi[nt], acc[mt][nt], 0, 0, 0);
            acc[mt][nt] = __builtin_amdgcn_mfma_f32_16x16x32_bf16(
                af[ks][mt], blo[nt], acc[mt][nt], 0, 0, 0);
          }
    }

    // ---- epilogue ----
    #pragma unroll
    for (int mt = 0; mt < 2; ++mt) {
      #pragma unroll
      for (int r = 0; r < 4; ++r) {
        float p = 0.f;
        #pragma unroll
        for (int nt = 0; nt < 4; ++nt) {
            const float h2 = fmaxf(acc[mt][nt][r] + b2f[nt], 0.f); // D: row=q*4+r, col=n
            p = fmaf(h2, w3f[nt], p);
        }
        p += __shfl_xor(p, 1);
        p += __shfl_xor(p, 2);
        p += __shfl_xor(p, 4);
        p += __shfl_xor(p, 8);
        if (n == mt * 4 + r) {
            const int item = wv * 32 + mt * 16 + q * 4 + r;
            if constexpr (ISF32) ((float*)out)[b * 128 + item] = p + b3f;
            else ((__hip_bfloat16*)out)[b * 128 + item] = __float2bfloat16(p + b3f);
        }
      }
    }
}

__global__ __launch_bounds__(256, 4) void qtranB_kernel(
    const void* __restrict__ hidden,   // dtype vote only
    const void* __restrict__ w1, const void* __restrict__ b2,
    const void* __restrict__ w3, const void* __restrict__ b3,
    void* __restrict__ out, const float* __restrict__ ws)
{
    __shared__ float corr_s[8][64];
    const int t = threadIdx.x;
    if (vote_isf32(hidden, t))
        qtranB_body<true>(corr_s, w1, b2, w3, b3, out, ws, blockIdx.x, t);
    else
        qtranB_body<false>(corr_s, w1, b2, w3, b3, out, ws, blockIdx.x, t);
}

// ================= Monolithic fallback (no/small workspace) =================
#define H1S 72
struct SmemM {
    float inp[384];
    float base[64];
    float sub[8][64];
    int   sel[8];
    union {
        float part[4][64];
        __align__(16) short h1[128 * H1S];
    } u;
};

template<bool ISF32>
__device__ void qtranM_body(SmemM& sm,
    const void* __restrict__ hidden, const void* __restrict__ actions,
    const void* __restrict__ w1, const void* __restrict__ b1,
    const void* __restrict__ w2, const void* __restrict__ b2,
    const void* __restrict__ w3, const void* __restrict__ b3,
    void* __restrict__ out, int b, int t)
{
    const int lane = t & 63;
    const int wv = t >> 6;
    const int q = lane >> 4;
    const int n = lane & 15;
    const int fq = lane & 15;
    const int rofs = lane >> 4;

    if (t < 64) {
        const int j = t >> 3, k4 = (t & 7) * 4;
        *(f32x4*)&sm.inp[j * 48 + k4] = ldq<ISF32>(hidden, (b * 8 + j) * 32 + k4);
    } else if (t < 96) {
        const int i = t - 64;
        const int j = i >> 2, c4 = (i & 3) * 4;
        *(f32x4*)&sm.inp[j * 48 + 32 + c4] = ldq<ISF32>(actions, (b * 8 + j) * 16 + c4);
    }
    __syncthreads();

    if (t < 128) {
        const int g = t >> 4, a = t & 15;
        if (sm.inp[g * 48 + 32 + a] > 0.5f) sm.sel[g] = a;
    }
    {
        f32x4 a4 = (f32x4){0.f, 0.f, 0.f, 0.f};
        #pragma unroll 8
        for (int p = 0; p < 16; ++p) {
            const int hr = wv * 64 + p * 4 + rofs;
            const int r = (hr >> 5) * 48 + (hr & 31);
            const float xv = sm.inp[r];
            const f32x4 wq = ldq<ISF32>(w1, r * 64 + fq * 4);
            #pragma unroll
            for (int c = 0; c < 4; ++c) a4[c] = fmaf(xv, wq[c], a4[c]);
        }
        #pragma unroll
        for (int c = 0; c < 4; ++c) {
            a4[c] += __shfl_xor(a4[c], 16);
            a4[c] += __shfl_xor(a4[c], 32);
        }
        if (rofs == 0) *(f32x4*)&sm.u.part[wv][fq * 4] = a4;
    }
    __syncthreads();

    if (t < 128) {
        const int g = t >> 4, f4 = (t & 15) * 4;
        *(f32x4*)&sm.sub[g][f4] =
            ldq<ISF32>(w1, (g * 48 + 32 + sm.sel[g]) * 64 + f4);
    } else if (t < 192) {
        const int f = t - 128;
        sm.base[f] = ldin<ISF32>(b1, f) + sm.u.part[0][f] + sm.u.part[1][f]
                   + sm.u.part[2][f] + sm.u.part[3][f];
    }
    __syncthreads();

    {
        const int itm = t >> 4;
        const int hfq = t & 15;
        f32x4 S = *(const f32x4*)&sm.sub[0][hfq * 4];
        #pragma unroll
        for (int g = 1; g < 8; ++g) {
            const f32x4 sg = *(const f32x4*)&sm.sub[g][hfq * 4];
            #pragma unroll
            for (int c = 0; c < 4; ++c) S[c] += sg[c];
        }
        f32x4 bs = *(const f32x4*)&sm.base[hfq * 4];
        #pragma unroll
        for (int c = 0; c < 4; ++c) bs[c] += S[c];
        #pragma unroll
        for (int p = 0; p < 8; ++p) {
            const int item = p * 16 + itm;
            const int g = item >> 4, a = item & 15;
            const f32x4 wq = ldq<ISF32>(w1, (g * 48 + 32 + a) * 64 + hfq * 4);
            const f32x4 sb = *(const f32x4*)&sm.sub[g][hfq * 4];
            s16x4 hi;
            #pragma unroll
            for (int c = 0; c < 4; ++c)
                hi[c] = bf16bits(fmaxf(bs[c] - sb[c] + wq[c], 0.f));
            *(s16x4*)&sm.u.h1[item * H1S + hfq * 4] = hi;
        }
    }
    __syncthreads();

    f32x4 acc[2][4];
    #pragma unroll
    for (int mt = 0; mt < 2; ++mt)
      #pragma unroll
      for (int nt = 0; nt < 4; ++nt)
        acc[mt][nt] = (f32x4){0.f, 0.f, 0.f, 0.f};

    #pragma unroll
    for (int ks = 0; ks < 2; ++ks) {
        bf16x8 ahi[2];
        #pragma unroll
        for (int mt = 0; mt < 2; ++mt) {
            const int item = wv * 32 + mt * 16 + n;
            ahi[mt] = *(const bf16x8*)&sm.u.h1[item * H1S + ks * 32 + q * 8];
        }
        bf16x8 bhi[4], blo[4];
        #pragma unroll
        for (int nt = 0; nt < 4; ++nt)
            #pragma unroll
            for (int j = 0; j < 8; ++j) {
                const float v = ldin<ISF32>(w2, (ks * 32 + q * 8 + j) * 64 + nt * 16 + n);
                const short hb = bf16bits(v);
                bhi[nt][j] = hb;
                blo[nt][j] = bf16bits(v - bf16val(hb));
            }
        #pragma unroll
        for (int nt = 0; nt < 4; ++nt)
            #pragma unroll
            for (int mt = 0; mt < 2; ++mt) {
                acc[mt][nt] = __builtin_amdgcn_mfma_f32_16x16x32_bf16(
                    ahi[mt], bhi[nt], acc[mt][nt], 0, 0, 0);
                acc[mt][nt] = __builtin_amdgcn_mfma_f32_16x16x32_bf16(
                    ahi[mt], blo[nt], acc[mt][nt], 0, 0, 0);
            }
    }

    float b2f[4], w3f[4];
    #pragma unroll
    for (int nt = 0; nt < 4; ++nt) {
        b2f[nt] = ldin<ISF32>(b2, nt * 16 + n);
        w3f[nt] = ldin<ISF32>(w3, nt * 16 + n);
    }
    const float b3f = ldin<ISF32>(b3, 0);

    #pragma unroll
    for (int mt = 0; mt < 2; ++mt) {
      #pragma unroll
      for (int r = 0; r < 4; ++r) {
        float p = 0.f;
        #pragma unroll
        for (int nt = 0; nt < 4; ++nt) {
            const float h2 = fmaxf(acc[mt][nt][r] + b2f[nt], 0.f);
            p = fmaf(h2, w3f[nt], p);
        }
        p += __shfl_xor(p, 1);
        p += __shfl_xor(p, 2);
        p += __shfl_xor(p, 4);
        p += __shfl_xor(p, 8);
        if (n == mt * 4 + r) {
            const int item = wv * 32 + mt * 16 + q * 4 + r;
            if constexpr (ISF32) ((float*)out)[b * 128 + item] = p + b3f;
            else ((__hip_bfloat16*)out)[b * 128 + item] = __float2bfloat16(p + b3f);
        }
      }
    }
}

__global__ __launch_bounds__(256, 4) void qtranM_kernel(
    const void* __restrict__ hidden, const void* __restrict__ actions,
    const void* __restrict__ w1, const void* __restrict__ b1,
    const void* __restrict__ w2, const void* __restrict__ b2,
    const void* __restrict__ w3, const void* __restrict__ b3,
    void* __restrict__ out)
{
    __shared__ SmemM sm;
    const int t = threadIdx.x;
    if (vote_isf32(hidden, t))
        qtranM_body<true>(sm, hidden, actions, w1, b1, w2, b2, w3, b3, out,
                          blockIdx.x, t);
    else
        qtranM_body<false>(sm, hidden, actions, w1, b1, w2, b2, w3, b3, out,
                           blockIdx.x, t);
}

extern "C" void kernel_launch(void* const* d_in, const int* in_sizes, int n_in,
                              void* d_out, int out_size, void* d_ws, size_t ws_size,
                              hipStream_t stream) {
    const size_t need = 16384 + (size_t)2048 * 8 * 64 * 4;  // frags + corr
    if (ws_size >= need) {
        float* ws = (float*)d_ws;
        qtranA_kernel<<<512, 256, 0, stream>>>(
            d_in[0], d_in[1], d_in[2], d_in[3], d_in[4], ws);
        qtranB_kernel<<<2048, 256, 0, stream>>>(
            d_in[0], d_in[2], d_in[5], d_in[6], d_in[7], d_out, ws);
    } else {
        qtranM_kernel<<<2048, 256, 0, stream>>>(
            d_in[0], d_in[1], d_in[2], d_in[3], d_in[4], d_in[5], d_in[6], d_in[7],
            d_out);
    }
}

// Round 11
// 83.173 us; speedup vs baseline: 1.0807x; 1.0807x over previous
//
#include <hip/hip_runtime.h>
#include <hip/hip_bf16.h>

typedef __attribute__((ext_vector_type(4))) float f32x4;
typedef __attribute__((ext_vector_type(8))) short bf16x8;
typedef __attribute__((ext_vector_type(4))) short s16x4;

#define H1S 72  // padded bf16 stride (144 B rows: 16B-aligned)

struct Smem {
    float inp[384];          // base input vector (real actions), f32
    float base[64];          // b1 + hidden-part of layer 1 (no action rows)
    float sub[8][64];        // sub[g][f] = W1 row of agent g's real action
    int   sel[8];            // real-action index per agent
    union {                  // part's last read is barrier-separated from h1's first write
        float part[4][64];
        __align__(16) short h1[128 * H1S];  // h1 in bf16
    } u;
};

template<bool ISF32>
__device__ __forceinline__ float ldin(const void* p, int i) {
    if constexpr (ISF32) return ((const float*)p)[i];
    else return __bfloat162float(((const __hip_bfloat16*)p)[i]);
}

template<bool ISF32>
__device__ __forceinline__ f32x4 ldq(const void* p, int i) {
    if constexpr (ISF32) return *(const f32x4*)((const float*)p + i);
    else {
        const __hip_bfloat16* q = (const __hip_bfloat16*)p + i;
        return (f32x4){__bfloat162float(q[0]), __bfloat162float(q[1]),
                       __bfloat162float(q[2]), __bfloat162float(q[3])};
    }
}

__device__ __forceinline__ short bf16bits(float v) {
    __hip_bfloat16 h = __float2bfloat16(v);
    return *(const short*)&h;
}
__device__ __forceinline__ float bf16val(short s) {
    return __bfloat162float(*(const __hip_bfloat16*)&s);
}

__device__ __forceinline__ bool word_looks_bf16(unsigned int w) {
    const unsigned int lo = w & 0xFFFFu;
    const unsigned int ex = (lo >> 7) & 0xFFu;
    return (ex >= 100u && ex <= 140u) || (lo & 0x7FFFu) == 0u;
}

template<bool ISF32>
__device__ void qtran_body(Smem& sm,
    const void* __restrict__ hidden, const void* __restrict__ actions,
    const void* __restrict__ w1, const void* __restrict__ b1,
    const void* __restrict__ w2, const void* __restrict__ b2,
    const void* __restrict__ w3, const void* __restrict__ b3,
    void* __restrict__ out, int b, int t)
{
    const int lane = t & 63;
    const int wv = t >> 6;
    const int q = lane >> 4;
    const int n = lane & 15;
    const int fq = lane & 15;
    const int rofs = lane >> 4;

    // ---- phase 0: stage input vector (f32x4 loads) ----
    if (t < 64) {
        const int j = t >> 3, k4 = (t & 7) * 4;
        *(f32x4*)&sm.inp[j * 48 + k4] = ldq<ISF32>(hidden, (b * 8 + j) * 32 + k4);
    } else if (t < 96) {
        const int i = t - 64;
        const int j = i >> 2, c4 = (i & 3) * 4;
        *(f32x4*)&sm.inp[j * 48 + 32 + c4] = ldq<ISF32>(actions, (b * 8 + j) * 16 + c4);
    }
    __syncthreads();

    // ---- phase 1a: find each agent's real-action index (one-hot) ----
    if (t < 128) {
        const int g = t >> 4, a = t & 15;
        if (sm.inp[g * 48 + 32 + a] > 0.5f) sm.sel[g] = a;
    }

    // ---- phase 1: hidden-row layer-1 partials; wave wv covers 64 of 256 rows ----
    {
        f32x4 a4 = (f32x4){0.f, 0.f, 0.f, 0.f};
        #pragma unroll 8
        for (int p = 0; p < 16; ++p) {
            const int hr = wv * 64 + p * 4 + rofs;   // hidden-row 0..255
            const int r = (hr >> 5) * 48 + (hr & 31);
            const float xv = sm.inp[r];
            const f32x4 wq = ldq<ISF32>(w1, r * 64 + fq * 4);
            #pragma unroll
            for (int c = 0; c < 4; ++c) a4[c] = fmaf(xv, wq[c], a4[c]);
        }
        #pragma unroll
        for (int c = 0; c < 4; ++c) {
            a4[c] += __shfl_xor(a4[c], 16);
            a4[c] += __shfl_xor(a4[c], 32);
        }
        if (rofs == 0) *(f32x4*)&sm.u.part[wv][fq * 4] = a4;
    }
    __syncthreads();

    // ---- phase 2: sub rows / base, disjoint thread groups ----
    if (t < 128) {
        const int g = t >> 4, f4 = (t & 15) * 4;
        *(f32x4*)&sm.sub[g][f4] =
            ldq<ISF32>(w1, (g * 48 + 32 + sm.sel[g]) * 64 + f4);
    } else if (t < 192) {
        const int f = t - 128;
        sm.base[f] = ldin<ISF32>(b1, f) + sm.u.part[0][f] + sm.u.part[1][f]
                   + sm.u.part[2][f] + sm.u.part[3][f];
    }
    __syncthreads();

    // ---- phase 4: h1 for 128 items -> bf16 LDS ----
    {
        const int itm = t >> 4;                      // 16 items per pass
        const int hfq = t & 15;
        f32x4 S = *(const f32x4*)&sm.sub[0][hfq * 4];
        #pragma unroll
        for (int g = 1; g < 8; ++g) {
            const f32x4 sg = *(const f32x4*)&sm.sub[g][hfq * 4];
            #pragma unroll
            for (int c = 0; c < 4; ++c) S[c] += sg[c];
        }
        f32x4 bs = *(const f32x4*)&sm.base[hfq * 4];
        #pragma unroll
        for (int c = 0; c < 4; ++c) bs[c] += S[c];   // base incl. all real actions
        #pragma unroll
        for (int p = 0; p < 8; ++p) {
            const int item = p * 16 + itm;
            const int g = item >> 4, a = item & 15;
            const f32x4 wq = ldq<ISF32>(w1, (g * 48 + 32 + a) * 64 + hfq * 4);
            const f32x4 sb = *(const f32x4*)&sm.sub[g][hfq * 4];
            s16x4 hi;
            #pragma unroll
            for (int c = 0; c < 4; ++c)
                hi[c] = bf16bits(fmaxf(bs[c] - sb[c] + wq[c], 0.f));
            *(s16x4*)&sm.u.h1[item * H1S + hfq * 4] = hi;
        }
    }
    __syncthreads();

    // ---- phase 5: layer 2; B-frags built from w2 directly (L2-hot) ----
    f32x4 acc[2][4];
    #pragma unroll
    for (int mt = 0; mt < 2; ++mt)
      #pragma unroll
      for (int nt = 0; nt < 4; ++nt)
        acc[mt][nt] = (f32x4){0.f, 0.f, 0.f, 0.f};

    #pragma unroll
    for (int ks = 0; ks < 2; ++ks) {
        bf16x8 ahi[2];
        #pragma unroll
        for (int mt = 0; mt < 2; ++mt) {
            const int item = wv * 32 + mt * 16 + n;  // A[m=lane&15][k=quad*8+j]
            ahi[mt] = *(const bf16x8*)&sm.u.h1[item * H1S + ks * 32 + q * 8];
        }
        bf16x8 bhi[4], blo[4];
        #pragma unroll
        for (int nt = 0; nt < 4; ++nt)
            #pragma unroll
            for (int j = 0; j < 8; ++j) {
                const float v = ldin<ISF32>(w2, (ks * 32 + q * 8 + j) * 64 + nt * 16 + n);
                const short hb = bf16bits(v);
                bhi[nt][j] = hb;
                blo[nt][j] = bf16bits(v - bf16val(hb));
            }
        #pragma unroll
        for (int nt = 0; nt < 4; ++nt)
            #pragma unroll
            for (int mt = 0; mt < 2; ++mt) {
                acc[mt][nt] = __builtin_amdgcn_mfma_f32_16x16x32_bf16(
                    ahi[mt], bhi[nt], acc[mt][nt], 0, 0, 0);
                acc[mt][nt] = __builtin_amdgcn_mfma_f32_16x16x32_bf16(
                    ahi[mt], blo[nt], acc[mt][nt], 0, 0, 0);
            }
    }

    // ---- epilogue: h2 = relu(acc + b2); qv = h2 . w3 + b3 ----
    float b2f[4], w3f[4];
    #pragma unroll
    for (int nt = 0; nt < 4; ++nt) {
        b2f[nt] = ldin<ISF32>(b2, nt * 16 + n);
        w3f[nt] = ldin<ISF32>(w3, nt * 16 + n);
    }
    const float b3f = ldin<ISF32>(b3, 0);

    #pragma unroll
    for (int mt = 0; mt < 2; ++mt) {
      #pragma unroll
      for (int r = 0; r < 4; ++r) {
        float p = 0.f;
        #pragma unroll
        for (int nt = 0; nt < 4; ++nt) {
            const float h2 = fmaxf(acc[mt][nt][r] + b2f[nt], 0.f); // D: row=q*4+r, col=n
            p = fmaf(h2, w3f[nt], p);
        }
        p += __shfl_xor(p, 1);
        p += __shfl_xor(p, 2);
        p += __shfl_xor(p, 4);
        p += __shfl_xor(p, 8);
        if (n == mt * 4 + r) {
            const int item = wv * 32 + mt * 16 + q * 4 + r;
            if constexpr (ISF32) ((float*)out)[b * 128 + item] = p + b3f;
            else ((__hip_bfloat16*)out)[b * 128 + item] = __float2bfloat16(p + b3f);
        }
      }
    }
}

__global__ __launch_bounds__(256, 4) void qtran_cf_kernel(
    const void* __restrict__ hidden, const void* __restrict__ actions,
    const void* __restrict__ w1, const void* __restrict__ b1,
    const void* __restrict__ w2, const void* __restrict__ b2,
    const void* __restrict__ w3, const void* __restrict__ b3,
    void* __restrict__ out)
{
    __shared__ Smem sm;
    // dtype vote, lane-parallel
    const unsigned int* hw = (const unsigned int*)hidden;
    const bool pass = word_looks_bf16(hw[threadIdx.x & 31]);
    const unsigned long long m = __ballot(pass);
    const bool isf32 = (__popcll(m) < 32);

    const int b = blockIdx.x;
    const int t = threadIdx.x;
    if (isf32)
        qtran_body<true>(sm, hidden, actions, w1, b1, w2, b2, w3, b3, out, b, t);
    else
        qtran_body<false>(sm, hidden, actions, w1, b1, w2, b2, w3, b3, out, b, t);
}

extern "C" void kernel_launch(void* const* d_in, const int* in_sizes, int n_in,
                              void* d_out, int out_size, void* d_ws, size_t ws_size,
                              hipStream_t stream) {
    // Single launch: no prep kernel, no workspace dependency.
    qtran_cf_kernel<<<2048, 256, 0, stream>>>(
        d_in[0], d_in[1], d_in[2], d_in[3], d_in[4], d_in[5], d_in[6], d_in[7],
        d_out);
}